// Round 6
// baseline (298.364 us; speedup 1.0000x reference)
//
#include <hip/hip_runtime.h>

// Volume renderer: alpha-compositing over 192 samples per ray.
// v7: non-temporal output stores (L3 working-set protection) + asm load block.
//
// Post-mortem v2-v6: five structurally different kernels all ran ~103 us.
// v6's rocprof (VGPR=20) is physically impossible for its asm block (>=29
// live) -> stale binary suspected; v4/v5 (VGPR 36/32) were real and still
// 103 us => per-wave load scheduling is a dead lever.
//
// System model: 304 MB delivered / 103 us = 2.95 TB/s. Inputs (252 MB)
// nearly fit L3 (256 MB), but our 52 MB output writes + harness re-poison
// writes evict ~127 MB of input per iteration -- exactly the measured
// FETCH_SIZE. Half the reads pay HBM latency (~900cy) instead of L3
// (~400cy); under a per-CU outstanding-miss cap, delivered BW ~ 1/latency.
//
// v7: ALL output stores use __builtin_nontemporal_store (nt bit) so the
// streamed-once output does not evict the reused input from L3.
//   predicted: FETCH 124 MB -> 60-85 MB, dur 103 -> 80-90 us, VGPR >= 32.
//   VGPR==20 again => harness did not rebuild (infra tripwire).

#define NRAYS 65536
#define L 192
#define BORDER_W 1e10f
#define EPS_F 1e-10f

typedef float f32x4 __attribute__((ext_vector_type(4)));

// DPP helper: invalid-source / masked-row lanes receive `old` (identity).
template <int CTRL, int RMASK>
__device__ __forceinline__ float updpp(float old, float src) {
    return __int_as_float(__builtin_amdgcn_update_dpp(
        __float_as_int(old), __float_as_int(src), CTRL, RMASK, 0xf, false));
}

// Inclusive product scan across the 64-lane wave (6 DPP VALU ops).
__device__ __forceinline__ float wave_incl_prod(float p) {
    p *= updpp<0x111, 0xf>(1.0f, p);  // row_shr:1
    p *= updpp<0x112, 0xf>(1.0f, p);  // row_shr:2
    p *= updpp<0x114, 0xf>(1.0f, p);  // row_shr:4
    p *= updpp<0x118, 0xf>(1.0f, p);  // row_shr:8
    p *= updpp<0x142, 0xa>(1.0f, p);  // row_bcast:15 -> rows 1,3
    p *= updpp<0x143, 0xc>(1.0f, p);  // row_bcast:31 -> rows 2,3
    return p;
}

// Inclusive sum scan: after this, lane 63 holds the wave total.
#define SUMSCAN(v)                          \
    v += updpp<0x111, 0xf>(0.0f, v);        \
    v += updpp<0x112, 0xf>(0.0f, v);        \
    v += updpp<0x114, 0xf>(0.0f, v);        \
    v += updpp<0x118, 0xf>(0.0f, v);        \
    v += updpp<0x142, 0xa>(0.0f, v);        \
    v += updpp<0x143, 0xc>(0.0f, v);

__device__ __forceinline__ float fast_sigmoid(float x) {
    return __builtin_amdgcn_rcpf(1.0f + __expf(-x));
}

__global__ __launch_bounds__(256) void vol_render_kernel(
    const float* __restrict__ depth,   // [N, 192]
    const float* __restrict__ rgb,     // [N, 192, 3]
    const float* __restrict__ sigma,   // [N, 192]
    float* __restrict__ out)           // color N*3 | depth N | acc N | weights N*192
{
    const int lane = threadIdx.x & 63;
    const int wave = threadIdx.x >> 6;
    const int ray  = blockIdx.x * 4 + wave;

    const int  cl     = (lane < 48) ? lane : 47;   // clamped lane (no branch)
    const bool active = lane < 48;
    const size_t sbase = (size_t)ray * L + cl * 4;

    size_t i4 = sbase + 4;                          // boundary-depth index
    if (i4 > (size_t)NRAYS * L - 1) i4 = (size_t)NRAYS * L - 1;

    const float* dp  = depth + sbase;
    const float* sp  = sigma + sbase;
    const float* rp  = rgb + (size_t)ray * (L * 3) + cl * 12;
    const float* d4p = depth + i4;

    // ---- forced-MLP load block: 6 loads in flight, one waitcnt ----
    f32x4 dv, sv, r0, r1, r2;
    float d4;
    asm volatile(
        "global_load_dwordx4 %0, %6, off\n\t"
        "global_load_dwordx4 %1, %7, off\n\t"
        "global_load_dwordx4 %2, %8, off\n\t"
        "global_load_dwordx4 %3, %8, off offset:16\n\t"
        "global_load_dwordx4 %4, %8, off offset:32\n\t"
        "global_load_dword   %5, %9, off\n\t"
        "s_waitcnt vmcnt(0)"
        : "=&v"(dv), "=&v"(sv), "=&v"(r0), "=&v"(r1), "=&v"(r2), "=&v"(d4)
        : "v"(dp), "v"(sp), "v"(rp), "v"(d4p)
        : "memory");

    // ---- alpha / survival ----
    float delta0 = dv.y - dv.x;
    float delta1 = dv.z - dv.y;
    float delta2 = dv.w - dv.z;
    float delta3 = (lane == 47) ? BORDER_W : (d4 - dv.w);

    float e0 = __expf(-fmaxf(sv.x, 0.0f) * delta0);
    float e1 = __expf(-fmaxf(sv.y, 0.0f) * delta1);
    float e2 = __expf(-fmaxf(sv.z, 0.0f) * delta2);
    float e3 = __expf(-fmaxf(sv.w, 0.0f) * delta3);
    float surv0 = e0 + EPS_F, surv1 = e1 + EPS_F;
    float surv2 = e2 + EPS_F, surv3 = e3 + EPS_F;

    // in-lane prefix products
    float p01   = surv0 * surv1;
    float p012  = p01 * surv2;
    float p0123 = p012 * surv3;

    // sigmoids: independent of the scan -> scheduler interleaves them
    float g0 = fast_sigmoid(r0.x), g1 = fast_sigmoid(r0.y), g2 = fast_sigmoid(r0.z);
    float g3 = fast_sigmoid(r0.w), g4 = fast_sigmoid(r1.x), g5 = fast_sigmoid(r1.y);
    float g6 = fast_sigmoid(r1.z), g7 = fast_sigmoid(r1.w), g8 = fast_sigmoid(r2.x);
    float g9 = fast_sigmoid(r2.y), gA = fast_sigmoid(r2.z), gB = fast_sigmoid(r2.w);

    // ---- wave-wide inclusive product scan (DPP, VALU-only) ----
    float p = wave_incl_prod(p0123);

    float excl = __shfl_up(p, 1, 64);
    if (lane == 0) excl = 1.0f;

    // transmittance & weights for the 4 owned samples
    float T0 = excl;
    float T1 = excl * surv0;
    float T2 = excl * p01;
    float T3 = excl * p012;
    float w0 = (1.0f - e0) * T0;
    float w1 = (1.0f - e1) * T1;
    float w2 = (1.0f - e2) * T2;
    float w3 = (1.0f - e3) * T3;

    if (!active) { w0 = w1 = w2 = w3 = 0.0f; }

    // non-temporal coalesced weight store: do NOT evict input from L3
    if (active) {
        f32x4 wv = {w0, w1, w2, w3};
        __builtin_nontemporal_store(
            wv, reinterpret_cast<f32x4*>(out + (size_t)NRAYS * 5 + sbase));
    }

    float col0 = w0 * g0 + w1 * g3 + w2 * g6 + w3 * g9;
    float col1 = w0 * g1 + w1 * g4 + w2 * g7 + w3 * gA;
    float col2 = w0 * g2 + w1 * g5 + w2 * g8 + w3 * gB;
    float dep  = w0 * dv.x + w1 * dv.y + w2 * dv.z + w3 * dv.w;
    float acc  = w0 + w1 + w2 + w3;

    // ---- 5 wave sums via DPP sum-scan; totals land in lane 63 ----
    SUMSCAN(col0)
    SUMSCAN(col1)
    SUMSCAN(col2)
    SUMSCAN(dep)
    SUMSCAN(acc)

    if (lane == 63) {
        __builtin_nontemporal_store(col0, out + (size_t)ray * 3 + 0);
        __builtin_nontemporal_store(col1, out + (size_t)ray * 3 + 1);
        __builtin_nontemporal_store(col2, out + (size_t)ray * 3 + 2);
        __builtin_nontemporal_store(dep,  out + (size_t)NRAYS * 3 + ray);
        __builtin_nontemporal_store(acc,  out + (size_t)NRAYS * 4 + ray);
    }
}

extern "C" void kernel_launch(void* const* d_in, const int* in_sizes, int n_in,
                              void* d_out, int out_size, void* d_ws, size_t ws_size,
                              hipStream_t stream) {
    const float* depth = (const float*)d_in[0];
    const float* rgb   = (const float*)d_in[1];
    const float* sigma = (const float*)d_in[2];
    float* out = (float*)d_out;

    // 4 waves (rays) per 256-thread block
    dim3 grid(NRAYS / 4);
    dim3 block(256);
    vol_render_kernel<<<grid, block, 0, stream>>>(depth, rgb, sigma, out);
}